// Round 15
// baseline (409.036 us; speedup 1.0000x reference)
//
#include <hip/hip_runtime.h>
#include <hip/hip_fp16.h>

#define NB     4
#define H      512
#define W      512
#define ITERS  30
#define K      4             // max iterations fused per dispatch
#define TOLF   1e-05f
#define TOTAL  (NB*H*W*3)    // 3,145,728
#define BLK    512
#define NWAVES (BLK/64)      // 8
#define NBLKS  1024          // 4 images x 16x16 tiles of 32x32
#define HALO   8
#define EXT    48            // 32 + 2*HALO
#define LRS    48
#define LPS    (48*48)       // 2304
#define RRS    48            // rbt row stride (halfs) — 48 for aligned b64
#define RPS    (46*48)       // 2208 (46 rows)
#define NQ1    552           // stage-1 quads: 46 rows x 12 quad-cols (4 px)
#define NQ2    484           // stage-2 quads: 44 rows x 11 quad-cols (4 px)
#define TBIG   1000000

__device__ __forceinline__ int refl(int v, int n) {
    if (v < 0)  return -v;
    if (v >= n) return 2 * n - 2 - v;
    return v;
}

// One dispatch = up to K=4 fused RL iterations on a 32x32 tile, halo-8.
// R15 = R14 (403 us) + stage-2 remapped to span-4 quads: origin j==2 mod 4
// => rb-local window j-2..j+3 is one aligned b64 (4 halfs) + one b32
// (2 halfs) per ch-row — 2x fewer stage-2 LDS reads and half the guard/
// address overhead. Per-pair write guards + interior masks preserved
// (stage-2 exactness). Stage-1 span-4 b128 quads, BLK=512 @ (512,8),
// 4 blocks/CU, 32 waves/CU. Symmetric Gaussian => reflection commutes with
// conv (mirror band staged once). done-flag: optimistic run + deterministic
// partials scan; firing in the previous group => recompute from that
// group's intact source (period-3 buffer schedule).
__global__ __launch_bounds__(BLK, 8) void rl_group(
    const float* __restrict__ inputs,
    const float* __restrict__ gk,
    const float* __restrict__ gkf,
    const float* __restrict__ src,       // latent at group start
    const float* __restrict__ src_prev,  // latent at PREVIOUS group start
    float* __restrict__ dst,
    float* __restrict__ part,            // [30][1024] iteration partials
    int g)                               // 0..7 compute, 8 fixup
{
    __shared__ float  lat[3 * LPS];      // 27648 B
    __shared__ __half rbt[3 * RPS];      // 13248 B
    __shared__ float  wred[NWAVES];      // 32 B
    __shared__ int    s_tstar;           // 4 B   (total 40932 <= 40960)

    const int tid  = threadIdx.x;
    const int lane = tid & 63;
    const int wid  = tid >> 6;
    const int b    = blockIdx.x;
    const int n    = b >> 8;
    const int rtile= b & 255;
    const int ty0  = (rtile >> 4) << 5;
    const int tx0  = (rtile & 15) << 5;
    const bool xe0 = (tx0 == 0), xe1 = (tx0 + 32 == W);
    const bool ye0 = (ty0 == 0), ye1 = (ty0 + 32 == H);
    const bool edge = xe0 | xe1 | ye0 | ye1;
    const size_t nbase = (size_t)n * (H * W * 3);
    const float* inp_n = inputs + nbase;

    const int base      = (4 * g < ITERS) ? 4 * g : ITERS;
    const int prev_base = (g > 0) ? 4 * (g - 1) : 0;

    // ---- deterministic scan: first firing iteration among prior groups ----
    int tstar = TBIG;
    if (g > 0) {
        const int tmax = base;
        if (tid == 0) s_tstar = TBIG;
        __syncthreads();
        for (int t = wid; t < tmax; t += NWAVES) {
            double a = 0.0;
            for (int q = lane; q < NBLKS; q += 64)
                a += (double)part[t * NBLKS + q];
            #pragma unroll
            for (int off = 32; off; off >>= 1) a += __shfl_down(a, off, 64);
            if (lane == 0) {
                const float mean = (float)(a / (double)TOTAL);
                if (fabsf(1.0f - mean) < TOLF) atomicMin(&s_tstar, t);
            }
        }
        __syncthreads();
        tstar = s_tstar;
    }

    // ---- mode decision (block-uniform, identical across all blocks) ----
    int m;
    const float* lsrc;
    bool wr_part;
    if (g == 0) {
        m = K; lsrc = src; wr_part = true;
    } else if (tstar >= base) {
        if (g == 8) return;
        m = (ITERS - base < K) ? (ITERS - base) : K;
        lsrc = src; wr_part = true;
    } else if (tstar >= prev_base) {
        m = tstar - prev_base + 1; lsrc = src_prev; wr_part = false;
    } else {
        if (g == 8) return;
        for (int p = tid; p < 1024; p += BLK) {
            const int i = p >> 5, j = p & 31;
            const size_t o = nbase + ((size_t)(ty0 + i) * W + (tx0 + j)) * 3;
            dst[o] = src[o]; dst[o + 1] = src[o + 1]; dst[o + 2] = src[o + 2];
        }
        return;
    }

    // ---- stage-1 quad metadata (2 slots) ----
    // quad q: i = q/12 + 1 in [1,47), j = 4*(q%12) + 1 (== 1 mod 4)
    int q1lat[2], q1rb[2], q1mrg[2];
    int q1o0[2], q1o1[2], q1o2[2], q1o3[2];
    #pragma unroll
    for (int up = 0; up < 2; ++up) {
        const int q = tid + up * BLK;
        q1mrg[up] = -1;
        if (q < NQ1) {
            const int i = q / 12 + 1;
            const int j = 4 * (q - (i - 1) * 12) + 1;
            q1lat[up] = i * LRS + j;
            q1rb[up]  = (i - 1) * RRS + (j - 1);
            const int vm = min(i - 1, 46 - i);
            int cm = min(j - 1, 46 - j);
            cm = max(cm, min(j,     45 - j));
            cm = max(cm, min(j + 1, 44 - j));
            cm = max(cm, min(j + 2, 43 - j));
            q1mrg[up] = min(vm, cm);
            const int ry = refl(ty0 - HALO + i, H);
            q1o0[up] = (ry * W + refl(tx0 - HALO + j,     W)) * 3;
            q1o1[up] = (ry * W + refl(tx0 - HALO + j + 1, W)) * 3;
            q1o2[up] = (ry * W + refl(tx0 - HALO + j + 2, W)) * 3;
            q1o3[up] = (ry * W + refl(tx0 - HALO + j + 3, W)) * 3;
        }
    }

    // ---- stage-2 quad metadata (1 slot) ----
    // quad q: i = q/11 + 2 in [2,46), j = 4*(q%11) + 2 (== 2 mod 4)
    // rb local base = (i-2)*RRS + (j-2), (j-2) == 0 mod 4 => b64-aligned.
    int q2lat = 0, q2rb = 0, q2m0 = -1, q2m1 = -1, q2msk = 0;
    if (tid < NQ2) {
        const int i = tid / 11 + 2;
        const int j = 4 * (tid - (i - 2) * 11) + 2;
        q2lat = i * LRS + j;
        q2rb  = (i - 2) * RRS + (j - 2);
        const int vm = min(i - 2, 45 - i);
        q2m0 = min(vm, min(j - 2, 44 - j));       // pair (j, j+1)
        q2m1 = min(vm, min(j, 42 - j));           // pair (j+2, j+3)
        const bool iok = ((unsigned)(i - HALO) < 32u);
        q2msk = (iok && ((unsigned)(j     - HALO) < 32u) ? 1 : 0)
              | (iok && ((unsigned)(j + 1 - HALO) < 32u) ? 2 : 0)
              | (iok && ((unsigned)(j + 2 - HALO) < 32u) ? 4 : 0)
              | (iok && ((unsigned)(j + 3 - HALO) < 32u) ? 8 : 0);
    }

    // ---- stage 48x48 latent tile (in-image part) ----
    const float* s_n = lsrc + nbase;
    for (int p = tid; p < EXT * EXT; p += BLK) {
        const int i = p / EXT, j = p - i * EXT;
        const int gy = ty0 - HALO + i, gx = tx0 - HALO + j;
        if ((unsigned)gy < (unsigned)H && (unsigned)gx < (unsigned)W) {
            const float* sp = s_n + ((size_t)gy * W + gx) * 3;
            const int l = i * LRS + j;
            lat[l]           = sp[0];
            lat[LPS + l]     = sp[1];
            lat[2 * LPS + l] = sp[2];
        }
    }
    __syncthreads();

    // ---- mirror fixups (once): columns, then rows ----
    if (edge) {
        if (xe0) {
            for (int p = tid; p < 3 * EXT * HALO; p += BLK) {
                const int c = p / (EXT * HALO), rr = p - c * (EXT * HALO);
                const int i = rr / HALO, j = rr - i * HALO;
                lat[c * LPS + i * LRS + j] = lat[c * LPS + i * LRS + (16 - j)];
            }
        } else if (xe1) {
            for (int p = tid; p < 3 * EXT * HALO; p += BLK) {
                const int c = p / (EXT * HALO), rr = p - c * (EXT * HALO);
                const int i = rr / HALO, j2 = rr - i * HALO;
                lat[c * LPS + i * LRS + 40 + j2] = lat[c * LPS + i * LRS + (38 - j2)];
            }
        }
        __syncthreads();
        if (ye0) {
            for (int p = tid; p < 3 * HALO * EXT; p += BLK) {
                const int c = p / (HALO * EXT), rr = p - c * (HALO * EXT);
                const int i = rr / EXT, j = rr - i * EXT;
                lat[c * LPS + i * LRS + j] = lat[c * LPS + (16 - i) * LRS + j];
            }
        } else if (ye1) {
            for (int p = tid; p < 3 * HALO * EXT; p += BLK) {
                const int c = p / (HALO * EXT), rr = p - c * (HALO * EXT);
                const int i2 = rr / EXT, j = rr - i2 * EXT;
                lat[c * LPS + (40 + i2) * LRS + j] = lat[c * LPS + (38 - i2) * LRS + j];
            }
        }
        __syncthreads();
    }

    // ---- fused sub-iterations (2 barriers each) ----
    #pragma unroll
    for (int s = 0; s < K; ++s) {
        if (s >= m) break;

        // stage 1: rb = inp * rcp(conv(lat, k)) — span-4 quads (b128+b64).
        #pragma unroll
        for (int up = 0; up < 2; ++up) {
            if (2 * s <= q1mrg[up]) {
                const int lo = q1lat[up];
                const int ro = q1rb[up];
                #pragma unroll
                for (int c = 0; c < 3; ++c) {
                    const float* lc = &lat[c * LPS + lo];
                    float a0 = 0.f, a1 = 0.f, a2 = 0.f, a3 = 0.f;
                    #pragma unroll
                    for (int dy = 0; dy < 3; ++dy) {
                        const float* rp = lc + (dy - 1) * LRS;
                        const float4 F = *(const float4*)(rp - 1);   // j-1..j+2
                        const float2 G = *(const float2*)(rp + 3);   // j+3,j+4
                        const float w0 = gk[(dy * 3 + 0) * 3 + c];
                        const float w1 = gk[(dy * 3 + 1) * 3 + c];
                        const float w2 = gk[(dy * 3 + 2) * 3 + c];
                        a0 = fmaf(F.x, w0, fmaf(F.y, w1, fmaf(F.z, w2, a0)));
                        a1 = fmaf(F.y, w0, fmaf(F.z, w1, fmaf(F.w, w2, a1)));
                        a2 = fmaf(F.z, w0, fmaf(F.w, w1, fmaf(G.x, w2, a2)));
                        a3 = fmaf(F.w, w0, fmaf(G.x, w1, fmaf(G.y, w2, a3)));
                    }
                    const float r0 = inp_n[q1o0[up] + c] * __builtin_amdgcn_rcpf(a0);
                    const float r1 = inp_n[q1o1[up] + c] * __builtin_amdgcn_rcpf(a1);
                    const float r2 = inp_n[q1o2[up] + c] * __builtin_amdgcn_rcpf(a2);
                    const float r3 = inp_n[q1o3[up] + c] * __builtin_amdgcn_rcpf(a3);
                    *(__half2*)&rbt[c * RPS + ro]     = __floats2half2_rn(r0, r1);
                    *(__half2*)&rbt[c * RPS + ro + 2] = __floats2half2_rn(r2, r3);
                }
            }
        }
        __syncthreads();

        // stage 2: e = conv(rb, kf); lat *= e; esum over interior —
        // span-4 quads: window local j-2..j+3 = b64 (4 halfs) + b32 (2 halfs)
        // per ch-row; outputs e0..e3 from h0..h5; per-pair guards exact.
        float esum = 0.f;
        {
            const bool b0ok = (2 * s <= q2m0);
            const bool b1ok = (2 * s <= q2m1);
            if (b0ok | b1ok) {
                const int ro = q2rb;
                const int lo = q2lat;
                const int mk = q2msk;
                #pragma unroll
                for (int c = 0; c < 3; ++c) {
                    float e0 = 0.f, e1 = 0.f, e2 = 0.f, e3 = 0.f;
                    #pragma unroll
                    for (int dy = 0; dy < 3; ++dy) {
                        const __half* hp = &rbt[c * RPS + ro + dy * RRS];
                        const __half2 P0 = *(const __half2*)(hp);      // h0,h1
                        const __half2 P1 = *(const __half2*)(hp + 2);  // h2,h3
                        const __half2 P2 = *(const __half2*)(hp + 4);  // h4,h5
                        const float2 f0 = __half22float2(P0);
                        const float2 f1 = __half22float2(P1);
                        const float2 f2 = __half22float2(P2);
                        const float w0 = gkf[(dy * 3 + 0) * 3 + c];
                        const float w1 = gkf[(dy * 3 + 1) * 3 + c];
                        const float w2 = gkf[(dy * 3 + 2) * 3 + c];
                        e0 = fmaf(f0.x, w0, fmaf(f0.y, w1, fmaf(f1.x, w2, e0)));
                        e1 = fmaf(f0.y, w0, fmaf(f1.x, w1, fmaf(f1.y, w2, e1)));
                        e2 = fmaf(f1.x, w0, fmaf(f1.y, w1, fmaf(f2.x, w2, e2)));
                        e3 = fmaf(f1.y, w0, fmaf(f2.x, w1, fmaf(f2.y, w2, e3)));
                    }
                    if (b0ok) {
                        float2* Lp = (float2*)&lat[c * LPS + lo];
                        float2 lv = *Lp;
                        lv.x *= e0; lv.y *= e1;
                        *Lp = lv;
                        esum += (mk & 1) ? e0 : 0.f;
                        esum += (mk & 2) ? e1 : 0.f;
                    }
                    if (b1ok) {
                        float2* Lp = (float2*)&lat[c * LPS + lo + 2];
                        float2 lv = *Lp;
                        lv.x *= e2; lv.y *= e3;
                        *Lp = lv;
                        esum += (mk & 4) ? e2 : 0.f;
                        esum += (mk & 8) ? e3 : 0.f;
                    }
                }
            }
        }
        if (wr_part) {
            #pragma unroll
            for (int off = 32; off; off >>= 1) esum += __shfl_down(esum, off, 64);
            if (lane == 0) wred[wid] = esum;
        }
        __syncthreads();     // lat writes done AND wred ready
        if (wr_part && tid == 0) {
            float t = 0.f;
            #pragma unroll
            for (int w2 = 0; w2 < NWAVES; ++w2) t += wred[w2];
            part[(base + s) * NBLKS + b] = t;
        }
    }

    // ---- write interior [8,40)^2 to dst ----
    for (int p = tid; p < 1024; p += BLK) {
        const int i = p >> 5, j = p & 31;
        const int l = (i + HALO) * LRS + (j + HALO);
        float* op = dst + nbase + ((size_t)(ty0 + i) * W + (tx0 + j)) * 3;
        op[0] = lat[l];
        op[1] = lat[LPS + l];
        op[2] = lat[2 * LPS + l];
    }
}

extern "C" void kernel_launch(void* const* d_in, const int* in_sizes, int n_in,
                              void* d_out, int out_size, void* d_ws, size_t ws_size,
                              hipStream_t stream) {
    const float* inputs = (const float*)d_in[0];
    const float* gk     = (const float*)d_in[1];
    const float* gkf    = (const float*)d_in[2];
    float* out = (float*)d_out;

    // ws: [0 .. 128KB) iteration partials [30][1024] | buffer A | buffer B
    char* ws = (char*)d_ws;
    float* part = (float*)ws;
    float* A    = (float*)(ws + 131072);
    float* Bb   = (float*)(ws + 131072 + (size_t)TOTAL * sizeof(float));

    // period-3 schedule; X[g] = latent at start of group g. X[8] = out.
    const float* X[9] = { inputs, A, out, Bb, A, out, Bb, A, out };

    for (int g = 0; g < 9; ++g) {
        const float* s  = X[(g == 8) ? 7 : g];
        const float* sp = X[(g == 0) ? 0 : g - 1];
        float*       d  = (float*)((g == 8) ? X[8] : X[g + 1]);
        rl_group<<<NBLKS, BLK, 0, stream>>>(inputs, gk, gkf, s, sp, d, part, g);
    }
}